// Round 13
// baseline (254.958 us; speedup 1.0000x reference)
//
#include <hip/hip_runtime.h>
#include <math.h>

#define D_MODEL 768
#define NUM_HEADS 12
#define HEAD_DIM 64
#define SEQ 2048
#define BATCH 4
#define MROWS (BATCH * SEQ)   // 8192
#define HALF_D (D_MODEL / 2)  // 384

typedef __bf16    bf16x8 __attribute__((ext_vector_type(8)));
typedef _Float16  f16x4  __attribute__((ext_vector_type(4)));
typedef float     f32x4  __attribute__((ext_vector_type(4)));

// async global->LDS, 16B per lane; LDS dest = wave-uniform base + lane*16
__device__ __forceinline__ void gload_lds16(const void* gp, void* lp) {
    __builtin_amdgcn_global_load_lds(
        (const __attribute__((address_space(1))) unsigned int*)gp,
        (__attribute__((address_space(3))) unsigned int*)lp, 16, 0, 0);
}

// ---------------------------------------------------------------------------
// prep: X cast (blocks [0,3072)) + weight cast/transpose ([3072,3648)).
// ---------------------------------------------------------------------------
__global__ __launch_bounds__(256)
void prep(const float* __restrict__ X, __bf16* __restrict__ Xb,
          const float* __restrict__ W0, const float* __restrict__ W1,
          const float* __restrict__ W2, const float* __restrict__ W3,
          __bf16* __restrict__ T0, __bf16* __restrict__ T1,
          __bf16* __restrict__ T2, __bf16* __restrict__ T3)
{
    __shared__ float t[64][65];
    const int n   = blockIdx.x;
    const int tid = threadIdx.x;

    if (n < 3072) {
        size_t i = ((size_t)n * 256 + tid) * 8;
        float4 u = *(const float4*)(X + i);
        float4 v = *(const float4*)(X + i + 4);
        bf16x8 o;
        o[0]=(__bf16)u.x; o[1]=(__bf16)u.y; o[2]=(__bf16)u.z; o[3]=(__bf16)u.w;
        o[4]=(__bf16)v.x; o[5]=(__bf16)v.y; o[6]=(__bf16)v.z; o[7]=(__bf16)v.w;
        *(bf16x8*)(Xb + i) = o;
    } else {
        int m = n - 3072;
        int z = m / 144;
        int rem = m - z * 144;
        int by = rem / 12, bx = rem % 12;
        const float* W = z == 0 ? W0 : z == 1 ? W1 : z == 2 ? W2 : W3;
        __bf16*      T = z == 0 ? T0 : z == 1 ? T1 : z == 2 ? T2 : T3;

        const int r0 = by * 64, c0 = bx * 64;
        const int lx = tid & 63, g = tid >> 6;

        #pragma unroll
        for (int rr = 0; rr < 16; ++rr) {
            int r = g * 16 + rr;
            t[r][lx] = W[(size_t)(r0 + r) * D_MODEL + c0 + lx];
        }
        __syncthreads();

        const int nn = tid >> 2;
        const int kb = (tid & 3) * 16;
        bf16x8 o1, o2;
        #pragma unroll
        for (int mm = 0; mm < 8; ++mm) o1[mm] = (__bf16)t[kb + mm][nn];
        #pragma unroll
        for (int mm = 0; mm < 8; ++mm) o2[mm] = (__bf16)t[kb + 8 + mm][nn];
        __bf16* dst = T + (size_t)(c0 + nn) * D_MODEL + r0 + kb;
        *(bf16x8*)dst       = o1;
        *(bf16x8*)(dst + 8) = o2;
    }
}

// ---------------------------------------------------------------------------
// Fused QKV projection (R9 structure, best of 7 variants). RoPE inline with
// hoisted freq (j outer loop) + angle-addition chaining across the 4
// consecutive rows (44 transcendentals/thread vs 128).
// Q pre-scaled by 0.125. V written TRANSPOSED as fp16 (PV MFMA is f16 K=16).
// ---------------------------------------------------------------------------
__global__ __launch_bounds__(256)
void qkv_gemm(const __bf16* __restrict__ Xb,
              const __bf16* __restrict__ Wqt, const __bf16* __restrict__ Wkt,
              const __bf16* __restrict__ Wvt,
              const float* __restrict__ bq, const float* __restrict__ bk,
              const float* __restrict__ bv,
              __bf16* __restrict__ Qb, __bf16* __restrict__ Kb,
              _Float16* __restrict__ Vtb)
{
    __shared__ bf16x8 Asf[2][8][64];
    __shared__ bf16x8 Bsf[2][8][64];

    const int tid  = threadIdx.x;
    const int wv   = tid >> 6;
    const int ln   = tid & 63;
    const int t15  = ln & 15;
    const int quad = ln >> 4;
    const int wr = wv >> 1, wc = wv & 1;

    const int lin = blockIdx.x;          // 1152 blocks: c*64 + r
    const int c   = lin >> 6;
    const int r   = lin & 63;            // XCD = r % 8
    const int which = c / 6;             // 0=Q 1=K 2=V
    const int col0  = (c % 6) * 128;
    const int row0  = r * 128;

    const __bf16* Wt  = which == 0 ? Wqt : which == 1 ? Wkt : Wvt;
    const float* bias = which == 0 ? bq  : which == 1 ? bk  : bv;

    f32x4 acc[4][4];
    #pragma unroll
    for (int i = 0; i < 4; ++i)
        #pragma unroll
        for (int j = 0; j < 4; ++j) acc[i][j] = (f32x4){0.f,0.f,0.f,0.f};

    const __bf16* a0 = Xb + (size_t)(row0 + 16 * wv       + t15) * D_MODEL + 8 * quad;
    const __bf16* a1 = Xb + (size_t)(row0 + 16 * (wv + 4) + t15) * D_MODEL + 8 * quad;
    const __bf16* b0 = Wt + (size_t)(col0 + 16 * wv       + t15) * D_MODEL + 8 * quad;
    const __bf16* b1 = Wt + (size_t)(col0 + 16 * (wv + 4) + t15) * D_MODEL + 8 * quad;

    for (int k0 = 0; k0 < D_MODEL; k0 += 64) {
        __syncthreads();
        #pragma unroll
        for (int ks = 0; ks < 2; ++ks) {
            const int kk = k0 + 32 * ks;
            gload_lds16(a0 + kk, &Asf[ks][wv][0]);
            gload_lds16(a1 + kk, &Asf[ks][wv + 4][0]);
            gload_lds16(b0 + kk, &Bsf[ks][wv][0]);
            gload_lds16(b1 + kk, &Bsf[ks][wv + 4][0]);
        }
        __syncthreads();

        #pragma unroll
        for (int ks = 0; ks < 2; ++ks) {
            bf16x8 af[4], bfr[4];
            #pragma unroll
            for (int i = 0; i < 4; ++i) af[i]  = Asf[ks][4 * wr + i][ln];
            #pragma unroll
            for (int j = 0; j < 4; ++j) bfr[j] = Bsf[ks][4 * wc + j][ln];
            #pragma unroll
            for (int i = 0; i < 4; ++i)
                #pragma unroll
                for (int j = 0; j < 4; ++j)
                    acc[i][j] = __builtin_amdgcn_mfma_f32_16x16x32_bf16(af[i], bfr[j], acc[i][j], 0, 0, 0);
        }
    }

    if (which < 2) {
        __bf16* dst = (which ? Kb : Qb);
        const float oscale = (which == 0) ? 0.125f : 1.0f;
        #pragma unroll
        for (int j = 0; j < 4; ++j) {
            const int col = col0 + 64 * wc + 16 * j + t15;
            const float bval = bias[col];
            const int ne = col & ~1;
            const float fr = __expf((float)ne * (-9.210340371976184f / 768.0f));
            const float cf = __cosf(fr), sf = __sinf(fr);   // per-row rotation step
            const float sgn = (col & 1) ? 1.0f : -1.0f;
            #pragma unroll
            for (int i = 0; i < 4; ++i) {
                const int rowb = row0 + 64 * wr + 16 * i + 4 * quad;
                const int s0   = rowb & (SEQ - 1);
                float ang = (float)s0 * fr;
                float ca = __cosf(ang), sa = __sinf(ang);
                #pragma unroll
                for (int rr = 0; rr < 4; ++rr) {
                    const int rw = rowb + rr;
                    float val  = acc[i][j][rr] + bval;
                    float part = __shfl_xor(val, 1, 64);
                    dst[(size_t)rw * D_MODEL + col] = (__bf16)((val * ca + part * sgn * sa) * oscale);
                    float cn = ca * cf - sa * sf;           // rotate by fr
                    sa = sa * cf + ca * sf;
                    ca = cn;
                }
            }
        }
    } else {
        #pragma unroll
        for (int i = 0; i < 4; ++i) {
            const int rowb = row0 + 64 * wr + 16 * i + 4 * quad;
            #pragma unroll
            for (int j = 0; j < 4; ++j) {
                const int col = col0 + 64 * wc + 16 * j + t15;
                const float bval = bias[col];
                const int h = col >> 6, d = col & 63;
                const int bidx = rowb >> 11, s = rowb & (SEQ - 1);
                f16x4 pk;
                #pragma unroll
                for (int rr = 0; rr < 4; ++rr) pk[rr] = (_Float16)(acc[i][j][rr] + bval);
                *(f16x4*)(Vtb + ((size_t)(bidx * NUM_HEADS + h) * 64 + d) * SEQ + s) = pk;
            }
        }
    }
}

// ---------------------------------------------------------------------------
// Output projection (R12 version): 64x128 tile, 768 blocks = 3/CU.
// ---------------------------------------------------------------------------
__global__ __launch_bounds__(256)
void out_gemm(const __bf16* __restrict__ Ab, const __bf16* __restrict__ Wt,
              const float* __restrict__ bias, float* __restrict__ Cout)
{
    __shared__ bf16x8 Asf[2][4][64];    // 8 KB
    __shared__ bf16x8 Bsf[2][8][64];    // 16 KB

    const int tid  = threadIdx.x;
    const int wv   = tid >> 6;
    const int ln   = tid & 63;
    const int t15  = ln & 15;
    const int quad = ln >> 4;
    const int wr = wv >> 1, wc = wv & 1;

    const int lin  = blockIdx.x;         // 768 blocks: c*128 + r
    const int col0 = (lin >> 7) * 128;
    const int row0 = (lin & 127) * 64;

    f32x4 acc[2][4];
    #pragma unroll
    for (int i = 0; i < 2; ++i)
        #pragma unroll
        for (int j = 0; j < 4; ++j) acc[i][j] = (f32x4){0.f,0.f,0.f,0.f};

    for (int k0 = 0; k0 < D_MODEL; k0 += 64) {
        __syncthreads();
        #pragma unroll
        for (int u = 0; u < 6; ++u) {
            const int id = wv * 6 + u;
            const int ks = id / 12;
            const int w  = id % 12;
            if (w < 4) {
                const __bf16* src = Ab + (size_t)(row0 + 16 * w + t15) * D_MODEL
                                       + k0 + 32 * ks + 8 * quad;
                gload_lds16(src, &Asf[ks][w][0]);
            } else {
                const __bf16* src = Wt + (size_t)(col0 + 16 * (w - 4) + t15) * D_MODEL
                                       + k0 + 32 * ks + 8 * quad;
                gload_lds16(src, &Bsf[ks][w - 4][0]);
            }
        }
        __syncthreads();

        #pragma unroll
        for (int ks = 0; ks < 2; ++ks) {
            bf16x8 af[2], bfr[4];
            #pragma unroll
            for (int i = 0; i < 2; ++i) af[i]  = Asf[ks][2 * wr + i][ln];
            #pragma unroll
            for (int j = 0; j < 4; ++j) bfr[j] = Bsf[ks][4 * wc + j][ln];
            #pragma unroll
            for (int i = 0; i < 2; ++i)
                #pragma unroll
                for (int j = 0; j < 4; ++j)
                    acc[i][j] = __builtin_amdgcn_mfma_f32_16x16x32_bf16(af[i], bfr[j], acc[i][j], 0, 0, 0);
        }
    }

    #pragma unroll
    for (int i = 0; i < 2; ++i) {
        const int rowb = row0 + 32 * wr + 16 * i + 4 * quad;
        #pragma unroll
        for (int j = 0; j < 4; ++j) {
            const int col = col0 + 64 * wc + 16 * j + t15;
            const float bval = bias[col];
            #pragma unroll
            for (int rr = 0; rr < 4; ++rr)
                Cout[(size_t)(rowb + rr) * D_MODEL + col] = acc[i][j][rr] + bval;
        }
    }
}

// ---------------------------------------------------------------------------
// Flash attention v5: S^T trick kills the P LDS round-trip.
//   QK^T computed as S^T = mfma(Kfrag, Qfrag) -> C holds (key=4q+r, query=t15).
//   That register layout IS the A-operand layout of 16x16x16 MFMA, so
//   P = exp(S^T) feeds PV directly from registers (pack to fp16, no LDS).
//   V is fp16; K=16 V-fragments come from the staged tile via ds_read_b64.
//   l is a single lane-local scalar (query = t15), 2 shuffles at the end.
// LDS drops 50.4 -> 32 KB. LPT dispatch + masked-tile skip kept.
// ---------------------------------------------------------------------------
__device__ __forceinline__ void attn_tile(
    const bf16x8 (*Kbuf)[64], const _Float16* Vbuf /* [8][512] */,
    bf16x8 aq0, bf16x8 aq1,
    f32x4* o, float& lacc,
    int ln, int t15, int quad, int j0, int qglob, bool domask)
{
    // S^T = K Q^T  (A = K-frag, B = Q-frag; Q pre-scaled by 1/8)
    f32x4 s[4];
    #pragma unroll
    for (int c = 0; c < 4; ++c) {
        s[c] = (f32x4){0.f, 0.f, 0.f, 0.f};
        s[c] = __builtin_amdgcn_mfma_f32_16x16x32_bf16(Kbuf[c][ln],     aq0, s[c], 0, 0, 0);
        s[c] = __builtin_amdgcn_mfma_f32_16x16x32_bf16(Kbuf[4 + c][ln], aq1, s[c], 0, 0, 0);
    }

    // p = exp(s^T); mask key>query; lane-local l; pack to fp16 A-frags
    f16x4 pf[4];
    #pragma unroll
    for (int c = 0; c < 4; ++c)
        #pragma unroll
        for (int r = 0; r < 4; ++r) {
            float e = __expf(s[c][r]);
            if (domask && (j0 + 16 * c + 4 * quad + r > qglob)) e = 0.f;
            lacc += e;
            pf[c][r] = (_Float16)e;
        }

    // O^acc += P V : 16x16x16 f16 MFMA, P from registers, V frag = ds_read_b64
    #pragma unroll
    for (int c = 0; c < 4; ++c) {
        const int lv = 16 * (2 * (c & 1) + (quad >> 1)) + t15;
        const int jb = 4 * (quad & 1);
        #pragma unroll
        for (int cd = 0; cd < 4; ++cd) {
            f16x4 vf = *(const f16x4*)&Vbuf[(size_t)(4 * (c >> 1) + cd) * 512 + lv * 8 + jb];
            o[cd] = __builtin_amdgcn_mfma_f32_16x16x16f16(pf[c], vf, o[cd], 0, 0, 0);
        }
    }
}

__global__ __launch_bounds__(512)
void attn_flash(const __bf16* __restrict__ Q, const __bf16* __restrict__ K,
                const _Float16* __restrict__ Vt, __bf16* __restrict__ O)
{
    __shared__ bf16x8   Kf[2][8][64];   // 16 KB (double-buffered)
    __shared__ _Float16 Vh[2][8][512];  // 16 KB (chunk f: lane*8 + j halfs)

    const int tid  = threadIdx.x;
    const int wv   = tid >> 6;
    const int ln   = tid & 63;
    const int t15  = ln & 15;
    const int quad = ln >> 4;

    const int n  = blockIdx.x;          // LPT: longest q-tiles first
    const int qt = 15 - (n / 48);
    const int bh = n % 48;
    const int b  = bh / NUM_HEADS;
    const int h  = bh % NUM_HEADS;
    const int q0 = qt * 128;
    const int nt = (q0 >> 6) + 2;

    bf16x8 aq0, aq1;
    {
        const __bf16* qs = Q + (size_t)(b * SEQ + q0 + 16 * wv + t15) * D_MODEL + h * 64 + 8 * quad;
        aq0 = *(const bf16x8*)qs;
        aq1 = *(const bf16x8*)(qs + 32);
    }

    const __bf16*   kp = K  + ((size_t)b * SEQ + 16 * (wv & 3) + t15) * D_MODEL
                            + h * 64 + 32 * (wv >> 2) + 8 * quad;
    const _Float16* vp = Vt + ((size_t)bh * 64 + 16 * (wv & 3) + t15) * SEQ
                            + 32 * (wv >> 2) + 8 * quad;

    f32x4 o[4];
    #pragma unroll
    for (int c = 0; c < 4; ++c) o[c] = (f32x4){0.f,0.f,0.f,0.f};
    float lacc = 0.f;
    const int qglob = q0 + 16 * wv + t15;   // this lane's query row
    const int wmax  = q0 + 16 * wv + 15;    // wave's last query row

    gload_lds16(kp, &Kf[0][wv][0]);
    gload_lds16(vp, &Vh[0][wv][0]);

    int cur = 0;
    for (int it = 0; it < nt; ++it) {
        __syncthreads();
        if (it + 1 < nt) {
            const int jn = (it + 1) * 64;
            gload_lds16(kp + (size_t)jn * D_MODEL, &Kf[cur ^ 1][wv][0]);
            gload_lds16(vp + jn,                   &Vh[cur ^ 1][wv][0]);
        }
        const int j0 = it * 64;
        if (j0 <= wmax) {                // skip fully-masked tiles
            const bool domask = (j0 + 63) > (q0 + 16 * wv);
            attn_tile(Kf[cur], &Vh[cur][0][0], aq0, aq1, o, lacc,
                      ln, t15, quad, j0, qglob, domask);
        }
        cur ^= 1;
    }

    // l lives per lane (query = t15): reduce over the 4 quads, then
    // redistribute to the C-layout rows (query = 4*quad + r).
    lacc += __shfl_xor(lacc, 16, 64);
    lacc += __shfl_xor(lacc, 32, 64);

    float inv[4];
    #pragma unroll
    for (int r = 0; r < 4; ++r)
        inv[r] = 1.0f / __shfl(lacc, 4 * quad + r, 64);

    #pragma unroll
    for (int c = 0; c < 4; ++c)
        #pragma unroll
        for (int r = 0; r < 4; ++r) {
            int row = q0 + 16 * wv + 4 * quad + r;
            O[(size_t)(b * SEQ + row) * D_MODEL + h * 64 + 16 * c + t15] = (__bf16)(o[c][r] * inv[r]);
        }
}

// ---------------------------------------------------------------------------
extern "C" void kernel_launch(void* const* d_in, const int* in_sizes, int n_in,
                              void* d_out, int out_size, void* d_ws, size_t ws_size,
                              hipStream_t stream) {
    const float* X  = (const float*)d_in[0];
    const float* Wq = (const float*)d_in[1];
    const float* bq = (const float*)d_in[2];
    const float* Wk = (const float*)d_in[3];
    const float* bk = (const float*)d_in[4];
    const float* Wv = (const float*)d_in[5];
    const float* bv = (const float*)d_in[6];
    const float* Wo = (const float*)d_in[7];
    const float* bo = (const float*)d_in[8];
    float* out = (float*)d_out;

    const size_t BSD = (size_t)MROWS * D_MODEL;   // 6,291,456
    const size_t WSZ = (size_t)D_MODEL * D_MODEL; //   589,824

    __bf16*   Xb  = (__bf16*)d_ws;
    __bf16*   Qb  = Xb  + BSD;
    __bf16*   Kb  = Qb  + BSD;
    _Float16* Vtb = (_Float16*)(Kb + BSD);
    __bf16*   Ob  = (__bf16*)(Vtb + BSD);
    __bf16*   Wqt = Ob  + BSD;
    __bf16*   Wkt = Wqt + WSZ;
    __bf16*   Wvt = Wkt + WSZ;
    __bf16*   Wot = Wvt + WSZ;

    prep<<<3648, 256, 0, stream>>>(X, Xb, Wq, Wk, Wv, Wo, Wqt, Wkt, Wvt, Wot);

    qkv_gemm<<<1152, 256, 0, stream>>>(Xb, Wqt, Wkt, Wvt, bq, bk, bv, Qb, Kb, Vtb);

    attn_flash<<<768, 512, 0, stream>>>(Qb, Kb, Vtb, Ob);

    out_gemm<<<768, 256, 0, stream>>>(Ob, Wot, bo, out);
}

// Round 14
// 243.526 us; speedup vs baseline: 1.0469x; 1.0469x over previous
//
#include <hip/hip_runtime.h>
#include <math.h>

#define D_MODEL 768
#define NUM_HEADS 12
#define HEAD_DIM 64
#define SEQ 2048
#define BATCH 4
#define MROWS (BATCH * SEQ)   // 8192
#define HALF_D (D_MODEL / 2)  // 384

typedef __bf16    bf16x8 __attribute__((ext_vector_type(8)));
typedef _Float16  f16x4  __attribute__((ext_vector_type(4)));
typedef float     f32x4  __attribute__((ext_vector_type(4)));

// async global->LDS, 16B per lane; LDS dest = wave-uniform base + lane*16
__device__ __forceinline__ void gload_lds16(const void* gp, void* lp) {
    __builtin_amdgcn_global_load_lds(
        (const __attribute__((address_space(1))) unsigned int*)gp,
        (__attribute__((address_space(3))) unsigned int*)lp, 16, 0, 0);
}

// ---------------------------------------------------------------------------
// prep: X cast (blocks [0,3072)) + weight cast/transpose ([3072,3648)).
// ---------------------------------------------------------------------------
__global__ __launch_bounds__(256)
void prep(const float* __restrict__ X, __bf16* __restrict__ Xb,
          const float* __restrict__ W0, const float* __restrict__ W1,
          const float* __restrict__ W2, const float* __restrict__ W3,
          __bf16* __restrict__ T0, __bf16* __restrict__ T1,
          __bf16* __restrict__ T2, __bf16* __restrict__ T3)
{
    __shared__ float t[64][65];
    const int n   = blockIdx.x;
    const int tid = threadIdx.x;

    if (n < 3072) {
        size_t i = ((size_t)n * 256 + tid) * 8;
        float4 u = *(const float4*)(X + i);
        float4 v = *(const float4*)(X + i + 4);
        bf16x8 o;
        o[0]=(__bf16)u.x; o[1]=(__bf16)u.y; o[2]=(__bf16)u.z; o[3]=(__bf16)u.w;
        o[4]=(__bf16)v.x; o[5]=(__bf16)v.y; o[6]=(__bf16)v.z; o[7]=(__bf16)v.w;
        *(bf16x8*)(Xb + i) = o;
    } else {
        int m = n - 3072;
        int z = m / 144;
        int rem = m - z * 144;
        int by = rem / 12, bx = rem % 12;
        const float* W = z == 0 ? W0 : z == 1 ? W1 : z == 2 ? W2 : W3;
        __bf16*      T = z == 0 ? T0 : z == 1 ? T1 : z == 2 ? T2 : T3;

        const int r0 = by * 64, c0 = bx * 64;
        const int lx = tid & 63, g = tid >> 6;

        #pragma unroll
        for (int rr = 0; rr < 16; ++rr) {
            int r = g * 16 + rr;
            t[r][lx] = W[(size_t)(r0 + r) * D_MODEL + c0 + lx];
        }
        __syncthreads();

        const int nn = tid >> 2;
        const int kb = (tid & 3) * 16;
        bf16x8 o1, o2;
        #pragma unroll
        for (int mm = 0; mm < 8; ++mm) o1[mm] = (__bf16)t[kb + mm][nn];
        #pragma unroll
        for (int mm = 0; mm < 8; ++mm) o2[mm] = (__bf16)t[kb + 8 + mm][nn];
        __bf16* dst = T + (size_t)(c0 + nn) * D_MODEL + r0 + kb;
        *(bf16x8*)dst       = o1;
        *(bf16x8*)(dst + 8) = o2;
    }
}

// ---------------------------------------------------------------------------
// Fused QKV projection (R9 core). Epilogue: R12's i-outer/j-inner store order
// (R13's j-outer order cost +20MB HBM writes from broken line assembly) with
// the angle-addition chain kept inside the rr loop (48 transcendentals).
// Q pre-scaled by 0.125; V written transposed as fp16 for the S^T attention.
// ---------------------------------------------------------------------------
__global__ __launch_bounds__(256)
void qkv_gemm(const __bf16* __restrict__ Xb,
              const __bf16* __restrict__ Wqt, const __bf16* __restrict__ Wkt,
              const __bf16* __restrict__ Wvt,
              const float* __restrict__ bq, const float* __restrict__ bk,
              const float* __restrict__ bv,
              __bf16* __restrict__ Qb, __bf16* __restrict__ Kb,
              _Float16* __restrict__ Vtb)
{
    __shared__ bf16x8 Asf[2][8][64];
    __shared__ bf16x8 Bsf[2][8][64];

    const int tid  = threadIdx.x;
    const int wv   = tid >> 6;
    const int ln   = tid & 63;
    const int t15  = ln & 15;
    const int quad = ln >> 4;
    const int wr = wv >> 1, wc = wv & 1;

    const int lin = blockIdx.x;          // 1152 blocks: c*64 + r
    const int c   = lin >> 6;
    const int r   = lin & 63;            // XCD = r % 8
    const int which = c / 6;             // 0=Q 1=K 2=V
    const int col0  = (c % 6) * 128;
    const int row0  = r * 128;

    const __bf16* Wt  = which == 0 ? Wqt : which == 1 ? Wkt : Wvt;
    const float* bias = which == 0 ? bq  : which == 1 ? bk  : bv;

    f32x4 acc[4][4];
    #pragma unroll
    for (int i = 0; i < 4; ++i)
        #pragma unroll
        for (int j = 0; j < 4; ++j) acc[i][j] = (f32x4){0.f,0.f,0.f,0.f};

    const __bf16* a0 = Xb + (size_t)(row0 + 16 * wv       + t15) * D_MODEL + 8 * quad;
    const __bf16* a1 = Xb + (size_t)(row0 + 16 * (wv + 4) + t15) * D_MODEL + 8 * quad;
    const __bf16* b0 = Wt + (size_t)(col0 + 16 * wv       + t15) * D_MODEL + 8 * quad;
    const __bf16* b1 = Wt + (size_t)(col0 + 16 * (wv + 4) + t15) * D_MODEL + 8 * quad;

    for (int k0 = 0; k0 < D_MODEL; k0 += 64) {
        __syncthreads();
        #pragma unroll
        for (int ks = 0; ks < 2; ++ks) {
            const int kk = k0 + 32 * ks;
            gload_lds16(a0 + kk, &Asf[ks][wv][0]);
            gload_lds16(a1 + kk, &Asf[ks][wv + 4][0]);
            gload_lds16(b0 + kk, &Bsf[ks][wv][0]);
            gload_lds16(b1 + kk, &Bsf[ks][wv + 4][0]);
        }
        __syncthreads();

        #pragma unroll
        for (int ks = 0; ks < 2; ++ks) {
            bf16x8 af[4], bfr[4];
            #pragma unroll
            for (int i = 0; i < 4; ++i) af[i]  = Asf[ks][4 * wr + i][ln];
            #pragma unroll
            for (int j = 0; j < 4; ++j) bfr[j] = Bsf[ks][4 * wc + j][ln];
            #pragma unroll
            for (int i = 0; i < 4; ++i)
                #pragma unroll
                for (int j = 0; j < 4; ++j)
                    acc[i][j] = __builtin_amdgcn_mfma_f32_16x16x32_bf16(af[i], bfr[j], acc[i][j], 0, 0, 0);
        }
    }

    #pragma unroll
    for (int i = 0; i < 4; ++i) {
        const int rowb = row0 + 64 * wr + 16 * i + 4 * quad;
        #pragma unroll
        for (int j = 0; j < 4; ++j) {
            const int col = col0 + 64 * wc + 16 * j + t15;
            const float bval = bias[col];
            if (which < 2) {
                const int ne = col & ~1;
                const float fr = __expf((float)ne * (-9.210340371976184f / 768.0f));
                const float cf = __cosf(fr), sf = __sinf(fr);   // rotation step per row
                const float sgn = (col & 1) ? 1.0f : -1.0f;
                const float oscale = (which == 0) ? 0.125f : 1.0f;
                __bf16* dst = (which ? Kb : Qb);
                const int s0 = rowb & (SEQ - 1);
                float ang = (float)s0 * fr;
                float ca = __cosf(ang), sa = __sinf(ang);
                #pragma unroll
                for (int rr = 0; rr < 4; ++rr) {
                    const int rw = rowb + rr;
                    float val  = acc[i][j][rr] + bval;
                    float part = __shfl_xor(val, 1, 64);
                    dst[(size_t)rw * D_MODEL + col] = (__bf16)((val * ca + part * sgn * sa) * oscale);
                    float cn = ca * cf - sa * sf;               // advance angle by fr
                    sa = sa * cf + ca * sf;
                    ca = cn;
                }
            } else {
                const int h = col >> 6, d = col & 63;
                const int bidx = rowb >> 11, s = rowb & (SEQ - 1);
                f16x4 pk;
                #pragma unroll
                for (int rr = 0; rr < 4; ++rr) pk[rr] = (_Float16)(acc[i][j][rr] + bval);
                *(f16x4*)(Vtb + ((size_t)(bidx * NUM_HEADS + h) * 64 + d) * SEQ + s) = pk;
            }
        }
    }
}

// ---------------------------------------------------------------------------
// Output projection (R12 version): 64x128 tile, 768 blocks = 3/CU.
// ---------------------------------------------------------------------------
__global__ __launch_bounds__(256)
void out_gemm(const __bf16* __restrict__ Ab, const __bf16* __restrict__ Wt,
              const float* __restrict__ bias, float* __restrict__ Cout)
{
    __shared__ bf16x8 Asf[2][4][64];    // 8 KB
    __shared__ bf16x8 Bsf[2][8][64];    // 16 KB

    const int tid  = threadIdx.x;
    const int wv   = tid >> 6;
    const int ln   = tid & 63;
    const int t15  = ln & 15;
    const int quad = ln >> 4;
    const int wr = wv >> 1, wc = wv & 1;

    const int lin  = blockIdx.x;         // 768 blocks: c*128 + r
    const int col0 = (lin >> 7) * 128;
    const int row0 = (lin & 127) * 64;

    f32x4 acc[2][4];
    #pragma unroll
    for (int i = 0; i < 2; ++i)
        #pragma unroll
        for (int j = 0; j < 4; ++j) acc[i][j] = (f32x4){0.f,0.f,0.f,0.f};

    for (int k0 = 0; k0 < D_MODEL; k0 += 64) {
        __syncthreads();
        #pragma unroll
        for (int u = 0; u < 6; ++u) {
            const int id = wv * 6 + u;
            const int ks = id / 12;
            const int w  = id % 12;
            if (w < 4) {
                const __bf16* src = Ab + (size_t)(row0 + 16 * w + t15) * D_MODEL
                                       + k0 + 32 * ks + 8 * quad;
                gload_lds16(src, &Asf[ks][w][0]);
            } else {
                const __bf16* src = Wt + (size_t)(col0 + 16 * (w - 4) + t15) * D_MODEL
                                       + k0 + 32 * ks + 8 * quad;
                gload_lds16(src, &Bsf[ks][w - 4][0]);
            }
        }
        __syncthreads();

        #pragma unroll
        for (int ks = 0; ks < 2; ++ks) {
            bf16x8 af[2], bfr[4];
            #pragma unroll
            for (int i = 0; i < 2; ++i) af[i]  = Asf[ks][2 * wr + i][ln];
            #pragma unroll
            for (int j = 0; j < 4; ++j) bfr[j] = Bsf[ks][4 * wc + j][ln];
            #pragma unroll
            for (int i = 0; i < 2; ++i)
                #pragma unroll
                for (int j = 0; j < 4; ++j)
                    acc[i][j] = __builtin_amdgcn_mfma_f32_16x16x32_bf16(af[i], bfr[j], acc[i][j], 0, 0, 0);
        }
    }

    #pragma unroll
    for (int i = 0; i < 2; ++i) {
        const int rowb = row0 + 32 * wr + 16 * i + 4 * quad;
        #pragma unroll
        for (int j = 0; j < 4; ++j) {
            const int col = col0 + 64 * wc + 16 * j + t15;
            const float bval = bias[col];
            #pragma unroll
            for (int rr = 0; rr < 4; ++rr)
                Cout[(size_t)(rowb + rr) * D_MODEL + col] = acc[i][j][rr] + bval;
        }
    }
}

// ---------------------------------------------------------------------------
// Flash attention v5 (unchanged from R13): S^T trick — P stays in registers
// (C-layout of S^T == A-layout of 16x16x16 f16 MFMA), no P LDS round-trip,
// V fp16 staged via global_load_lds, 32 KB LDS, LPT dispatch, masked skip.
// ---------------------------------------------------------------------------
__device__ __forceinline__ void attn_tile(
    const bf16x8 (*Kbuf)[64], const _Float16* Vbuf /* [8][512] */,
    bf16x8 aq0, bf16x8 aq1,
    f32x4* o, float& lacc,
    int ln, int t15, int quad, int j0, int qglob, bool domask)
{
    // S^T = K Q^T  (A = K-frag, B = Q-frag; Q pre-scaled by 1/8)
    f32x4 s[4];
    #pragma unroll
    for (int c = 0; c < 4; ++c) {
        s[c] = (f32x4){0.f, 0.f, 0.f, 0.f};
        s[c] = __builtin_amdgcn_mfma_f32_16x16x32_bf16(Kbuf[c][ln],     aq0, s[c], 0, 0, 0);
        s[c] = __builtin_amdgcn_mfma_f32_16x16x32_bf16(Kbuf[4 + c][ln], aq1, s[c], 0, 0, 0);
    }

    // p = exp(s^T); mask key>query; lane-local l; pack to fp16 A-frags
    f16x4 pf[4];
    #pragma unroll
    for (int c = 0; c < 4; ++c)
        #pragma unroll
        for (int r = 0; r < 4; ++r) {
            float e = __expf(s[c][r]);
            if (domask && (j0 + 16 * c + 4 * quad + r > qglob)) e = 0.f;
            lacc += e;
            pf[c][r] = (_Float16)e;
        }

    // O^acc += P V : 16x16x16 f16 MFMA, P from registers, V frag = ds_read_b64
    #pragma unroll
    for (int c = 0; c < 4; ++c) {
        const int lv = 16 * (2 * (c & 1) + (quad >> 1)) + t15;
        const int jb = 4 * (quad & 1);
        #pragma unroll
        for (int cd = 0; cd < 4; ++cd) {
            f16x4 vf = *(const f16x4*)&Vbuf[(size_t)(4 * (c >> 1) + cd) * 512 + lv * 8 + jb];
            o[cd] = __builtin_amdgcn_mfma_f32_16x16x16f16(pf[c], vf, o[cd], 0, 0, 0);
        }
    }
}

__global__ __launch_bounds__(512)
void attn_flash(const __bf16* __restrict__ Q, const __bf16* __restrict__ K,
                const _Float16* __restrict__ Vt, __bf16* __restrict__ O)
{
    __shared__ bf16x8   Kf[2][8][64];   // 16 KB (double-buffered)
    __shared__ _Float16 Vh[2][8][512];  // 16 KB

    const int tid  = threadIdx.x;
    const int wv   = tid >> 6;
    const int ln   = tid & 63;
    const int t15  = ln & 15;
    const int quad = ln >> 4;

    const int n  = blockIdx.x;          // LPT: longest q-tiles first
    const int qt = 15 - (n / 48);
    const int bh = n % 48;
    const int b  = bh / NUM_HEADS;
    const int h  = bh % NUM_HEADS;
    const int q0 = qt * 128;
    const int nt = (q0 >> 6) + 2;

    bf16x8 aq0, aq1;
    {
        const __bf16* qs = Q + (size_t)(b * SEQ + q0 + 16 * wv + t15) * D_MODEL + h * 64 + 8 * quad;
        aq0 = *(const bf16x8*)qs;
        aq1 = *(const bf16x8*)(qs + 32);
    }

    const __bf16*   kp = K  + ((size_t)b * SEQ + 16 * (wv & 3) + t15) * D_MODEL
                            + h * 64 + 32 * (wv >> 2) + 8 * quad;
    const _Float16* vp = Vt + ((size_t)bh * 64 + 16 * (wv & 3) + t15) * SEQ
                            + 32 * (wv >> 2) + 8 * quad;

    f32x4 o[4];
    #pragma unroll
    for (int c = 0; c < 4; ++c) o[c] = (f32x4){0.f,0.f,0.f,0.f};
    float lacc = 0.f;
    const int qglob = q0 + 16 * wv + t15;   // this lane's query row
    const int wmax  = q0 + 16 * wv + 15;    // wave's last query row

    gload_lds16(kp, &Kf[0][wv][0]);
    gload_lds16(vp, &Vh[0][wv][0]);

    int cur = 0;
    for (int it = 0; it < nt; ++it) {
        __syncthreads();
        if (it + 1 < nt) {
            const int jn = (it + 1) * 64;
            gload_lds16(kp + (size_t)jn * D_MODEL, &Kf[cur ^ 1][wv][0]);
            gload_lds16(vp + jn,                   &Vh[cur ^ 1][wv][0]);
        }
        const int j0 = it * 64;
        if (j0 <= wmax) {                // skip fully-masked tiles
            const bool domask = (j0 + 63) > (q0 + 16 * wv);
            attn_tile(Kf[cur], &Vh[cur][0][0], aq0, aq1, o, lacc,
                      ln, t15, quad, j0, qglob, domask);
        }
        cur ^= 1;
    }

    // l per lane (query = t15): reduce over quads, redistribute to C-layout rows
    lacc += __shfl_xor(lacc, 16, 64);
    lacc += __shfl_xor(lacc, 32, 64);

    float inv[4];
    #pragma unroll
    for (int r = 0; r < 4; ++r)
        inv[r] = 1.0f / __shfl(lacc, 4 * quad + r, 64);

    #pragma unroll
    for (int c = 0; c < 4; ++c)
        #pragma unroll
        for (int r = 0; r < 4; ++r) {
            int row = q0 + 16 * wv + 4 * quad + r;
            O[(size_t)(b * SEQ + row) * D_MODEL + h * 64 + 16 * c + t15] = (__bf16)(o[c][r] * inv[r]);
        }
}

// ---------------------------------------------------------------------------
extern "C" void kernel_launch(void* const* d_in, const int* in_sizes, int n_in,
                              void* d_out, int out_size, void* d_ws, size_t ws_size,
                              hipStream_t stream) {
    const float* X  = (const float*)d_in[0];
    const float* Wq = (const float*)d_in[1];
    const float* bq = (const float*)d_in[2];
    const float* Wk = (const float*)d_in[3];
    const float* bk = (const float*)d_in[4];
    const float* Wv = (const float*)d_in[5];
    const float* bv = (const float*)d_in[6];
    const float* Wo = (const float*)d_in[7];
    const float* bo = (const float*)d_in[8];
    float* out = (float*)d_out;

    const size_t BSD = (size_t)MROWS * D_MODEL;   // 6,291,456
    const size_t WSZ = (size_t)D_MODEL * D_MODEL; //   589,824

    __bf16*   Xb  = (__bf16*)d_ws;
    __bf16*   Qb  = Xb  + BSD;
    __bf16*   Kb  = Qb  + BSD;
    _Float16* Vtb = (_Float16*)(Kb + BSD);
    __bf16*   Ob  = (__bf16*)(Vtb + BSD);
    __bf16*   Wqt = Ob  + BSD;
    __bf16*   Wkt = Wqt + WSZ;
    __bf16*   Wvt = Wkt + WSZ;
    __bf16*   Wot = Wvt + WSZ;

    prep<<<3648, 256, 0, stream>>>(X, Xb, Wq, Wk, Wv, Wo, Wqt, Wkt, Wvt, Wot);

    qkv_gemm<<<1152, 256, 0, stream>>>(Xb, Wqt, Wkt, Wvt, bq, bk, bv, Qb, Kb, Vtb);

    attn_flash<<<768, 512, 0, stream>>>(Qb, Kb, Vtb, Ob);

    out_gemm<<<768, 256, 0, stream>>>(Ob, Wot, bo, out);
}